// Round 5
// baseline (8488.026 us; speedup 1.0000x reference)
//
#include <hip/hip_runtime.h>
#include <stdint.h>

#define T_IN  128
#define T_OUT 50
#define NW    4          // waves per block (256 threads)

typedef __bf16 bf16x8_t __attribute__((ext_vector_type(8)));
typedef float  f32x4_t  __attribute__((ext_vector_type(4)));

#define HROW_BYTES 176
#define HBUF_WAVE  (16 * HROW_BYTES)   // 2816 B per wave

#define LOG2E  1.4426950408889634f
#define LOG2E2 2.8853900817779268f

__device__ __forceinline__ float rcp_f(float x) { return __builtin_amdgcn_rcpf(x); }
__device__ __forceinline__ float ex2(float x)   { return __builtin_amdgcn_exp2f(x); }
__device__ __forceinline__ uint32_t pk(__bf16 a, __bf16 b) {
    return (uint32_t)__builtin_bit_cast(uint16_t, a) |
           ((uint32_t)__builtin_bit_cast(uint16_t, b) << 16);
}

// MFMA layout (verified m89/m91):
//   A  : A[m = lane&15][k = (lane>>4)*8 + j]
//   B  : B[k = (lane>>4)*8 + j][n = lane&15]
//   C/D: col = lane&15, row = (lane>>4)*4 + reg
// k-permutation pi(p) = (p>>2) + 16*(p&3) applied to both Whh k-columns and h
// stores. Slab2 ([x0,x1,1,0...]) identity layout, zero-padded over 32 lane
// slots (lanes>=31 clamp to the zero region via min(lane,31)).
//
// exp2 folding: weights/bias pre-scaled by log2e (i,f,o) / 2*log2e (g) at
// staging, so activations use bare v_exp_f32 (exp2) with free input negate.
//
// REGISTER BUDGET (rounds 2/3 post-mortem): cap 128 spilled ~85 dwords/step
// -> 31 GB scratch traffic. Cap 256 (round 4): 128 arch, no spill, but only
// 2 waves/SIMD -> VALUBusy 53%. This round: cap 170 via (256,3) + liveness
// diet (incremental h-pack, in-step fc accumulate, hoisted LDS bases).

template<bool DEC>
__device__ __forceinline__ void do_step(
    const uint8_t* __restrict__ haddr,  // hb + c*HROW + q*16   (A-frag base)
    uint8_t* __restrict__ hwr,          // hb + 4q*HROW + c*8   (h-store base)
    const uint8_t* __restrict__ fragp,  // sFrag + lane*16
    const uint8_t* __restrict__ b2p,    // sB2 + min(lane,31)*8
    uint32_t xpack, uint32_t bias1, bool q0,
    f32x4_t (&cst)[4],
    const float (&wf0)[4], const float (&wf1)[4],
    float (&s0)[4], float (&s1)[4])
{
    bf16x8_t a0 = *(const bf16x8_t*)(haddr);
    bf16x8_t a1 = *(const bf16x8_t*)(haddr + 64);
    union { bf16x8_t v; uint32_t u[4]; } ua;
    ua.u[0] = q0 ? xpack : 0u;
    ua.u[1] = bias1;                 // bf16 1.0 at k=2 (q==0 lanes)
    ua.u[2] = 0u; ua.u[3] = 0u;
    bf16x8_t a2 = ua.v;

    uint32_t hx[4], hy[4];
    f32x4_t hvprev;

    #pragma unroll
    for (int tc = 0; tc < 4; ++tc) {
        f32x4_t acc[4];   // gi: 0=i,1=f,2=g,3=o  (tile = tc + 4*gi)
        #pragma unroll
        for (int gi = 0; gi < 4; ++gi) {
            const int t = tc + gi * 4;
            bf16x8_t b0 = *(const bf16x8_t*)(fragp + t * 2048);
            bf16x8_t b1 = *(const bf16x8_t*)(fragp + t * 2048 + 1024);
            uint2 w2 = *(const uint2*)(b2p + t * 256);
            union { bf16x8_t v; uint32_t u[4]; } ub;
            ub.u[0] = w2.x; ub.u[1] = w2.y; ub.u[2] = 0u; ub.u[3] = 0u;
            f32x4_t z = {0.f, 0.f, 0.f, 0.f};
            f32x4_t a = __builtin_amdgcn_mfma_f32_16x16x32_bf16(a0, b0, z, 0, 0, 0);
            a = __builtin_amdgcn_mfma_f32_16x16x32_bf16(a1, b1, a, 0, 0, 0);
            acc[gi] = __builtin_amdgcn_mfma_f32_16x16x32_bf16(a2, ub.v, a, 0, 0, 0);
        }
        float ec[4], ogs[4];
        f32x4_t hv;
        #pragma unroll
        for (int r = 0; r < 4; ++r) {
            float ea  = ex2(-acc[0][r]);          // weights pre-scaled: bare exp2
            float efv = ex2(-acc[1][r]);
            float egv = ex2(-acc[2][r]);          // g-gate pre-scaled by 2*log2e
            float eov = ex2(-acc[3][r]);
            float pa = 1.f + ea, pfv = 1.f + efv, pg = 1.f + egv, po = 1.f + eov;
            float A  = pa * pg, Bq = pfv * po;
            float rr = rcp_f(A * Bq);
            float rA = rr * A;                    // = 1/(pf*po)
            float igp = (1.f - egv) * rr * Bq;    // = i*g
            float fgt = rA * po;                  // = sigmoid(f)
            float ogt = rA * pfv;                 // = sigmoid(o)
            float cn  = fgt * cst[tc][r] + igp;
            cst[tc][r] = cn;
            float y = fminf(fmaxf(cn * LOG2E2, -43.f), 43.f);
            ec[r]  = ex2(-y);
            ogs[r] = ogt;
        }
        #pragma unroll
        for (int rp = 0; rp < 2; ++rp) {
            float e0 = ec[2 * rp], e1 = ec[2 * rp + 1];
            float C0 = 1.f + e0, C1 = 1.f + e1;
            float rr2 = rcp_f(C0 * C1);
            hv[2 * rp]     = ogs[2 * rp]     * (1.f - e0) * rr2 * C1;
            hv[2 * rp + 1] = ogs[2 * rp + 1] * (1.f - e1) * rr2 * C0;
        }
        if constexpr (DEC) {
            #pragma unroll
            for (int r = 0; r < 4; ++r) {
                s0[r] += hv[r] * wf0[tc];
                s1[r] += hv[r] * wf1[tc];
            }
        }
        // incremental h-pack: kills the 16-reg hst array
        if (tc == 0 || tc == 2) {
            hvprev = hv;
        } else if (tc == 1) {
            #pragma unroll
            for (int r = 0; r < 4; ++r) hx[r] = pk((__bf16)hvprev[r], (__bf16)hv[r]);
        } else {
            #pragma unroll
            for (int r = 0; r < 4; ++r) hy[r] = pk((__bf16)hvprev[r], (__bf16)hv[r]);
        }
    }
    #pragma unroll
    for (int r = 0; r < 4; ++r) {
        uint2 u; u.x = hx[r]; u.y = hy[r];
        *(uint2*)(hwr + r * HROW_BYTES) = u;
    }
}

__global__ __launch_bounds__(256, 3) void seq2seq_lstm(
    const float* __restrict__ in_seq,
    const float* __restrict__ WihE, const float* __restrict__ WhhE,
    const float* __restrict__ bihE, const float* __restrict__ bhhE,
    const float* __restrict__ WihD, const float* __restrict__ WhhD,
    const float* __restrict__ bihD, const float* __restrict__ bhhD,
    const float* __restrict__ Wfc,  const float* __restrict__ bfc,
    float* __restrict__ out)
{
    __shared__ __align__(16) uint8_t sFrag[32768];          // 32 Whh B-frags
    __shared__ __align__(16) uint8_t sB2[4096];             // slab2, 32-slot padded
    __shared__ __align__(16) uint8_t sHbuf[NW * HBUF_WAVE]; // 11264
    __shared__ __align__(16) uint8_t sXbuf[NW * 1024];      // 4096
    // total 52224 B -> 3 blocks/CU (12 waves/CU) at VGPR cap 170

    const int tid  = threadIdx.x;
    const int lane = tid & 63;
    const int wave = tid >> 6;
    const int c    = lane & 15;
    const int q    = lane >> 4;

    auto stage_frags = [&](const float* Whh, const float* Wih,
                           const float* bih, const float* bhh) {
        #pragma unroll 1
        for (int it = 0; it < 8; ++it) {
            int idx = it * 256 + tid;   // 0..2047 = frag(0..31) x lane(0..63)
            int ln  = idx & 63;
            int fg  = idx >> 6;         // fg = tile*2 + kf
            int kf  = fg & 1;
            int t   = fg >> 1;
            int n   = ln & 15;
            int qq  = ln >> 4;
            float sc = ((t >> 2) == 2) ? LOG2E2 : LOG2E;   // g-gate: 2*log2e
            const float* wr = Whh + (t * 16 + n) * 64;
            uint32_t wv[4];
            #pragma unroll
            for (int jj = 0; jj < 4; ++jj) {
                int p0 = kf * 32 + qq * 8 + 2 * jj;
                int p1 = p0 + 1;
                int k0 = (p0 >> 2) + 16 * (p0 & 3);
                int k1 = (p1 >> 2) + 16 * (p1 & 3);
                wv[jj] = pk((__bf16)(sc * wr[k0]), (__bf16)(sc * wr[k1]));
            }
            uint32_t* d = (uint32_t*)(sFrag + fg * 1024 + ln * 16);
            d[0] = wv[0]; d[1] = wv[1]; d[2] = wv[2]; d[3] = wv[3];
        }
        // slab2: tile t at t*256, 32 slots x 8 B; slots 0..15 = {Wih row, bias}
        #pragma unroll 1
        for (int it = 0; it < 2; ++it) {
            int idx = it * 256 + tid;   // 0..511 = tile(0..15) x slot(0..31)
            int t  = idx >> 5;
            int sl = idx & 31;
            float sc = ((t >> 2) == 2) ? LOG2E2 : LOG2E;
            uint2 u = make_uint2(0u, 0u);
            if (sl < 16) {
                int n2 = t * 16 + sl;
                u.x = pk((__bf16)(sc * Wih[n2 * 2 + 0]), (__bf16)(sc * Wih[n2 * 2 + 1]));
                u.y = pk((__bf16)(sc * (bih[n2] + bhh[n2])), (__bf16)0.0f);
            }
            *(uint2*)(sB2 + t * 256 + sl * 8) = u;
        }
    };

    stage_frags(WhhE, WihE, bihE, bhhE);
    for (int i = tid; i < (NW * HBUF_WAVE) / 4; i += 256)
        ((uint32_t*)sHbuf)[i] = 0u;
    __syncthreads();
    // ---- no barriers inside the time loops: each wave owns its 16 rows ----

    uint8_t* hb  = sHbuf + wave * HBUF_WAVE;
    uint8_t* sXw = sXbuf + wave * 1024;
    const int rowBase = blockIdx.x * (NW * 16) + wave * 16;

    // loop-invariant LDS bases (per-tile offsets become immediates)
    const uint8_t* haddr = hb + c * HROW_BYTES + q * 16;
    uint8_t*       hwr   = hb + 4 * q * HROW_BYTES + c * 8;
    const uint8_t* fragp = sFrag + lane * 16;
    const uint8_t* b2p   = sB2 + (lane < 31 ? lane : 31) * 8;
    const uint32_t bias1 = (q == 0) ? 0x00003F80u : 0u;
    const bool     q0    = (q == 0);

    f32x4_t cst[4];
    #pragma unroll
    for (int tc = 0; tc < 4; ++tc) cst[tc] = (f32x4_t){0.f, 0.f, 0.f, 0.f};

    float wf0[4] = {0.f, 0.f, 0.f, 0.f}, wf1[4] = {0.f, 0.f, 0.f, 0.f};
    float s0t[4], s1t[4];

    // ================= encoder (8-step input chunks) =================
    const float* gsrc = in_seq + (size_t)(rowBase + (lane >> 2)) * (T_IN * 2)
                               + (lane & 3) * 4;
    float4 pf = *(const float4*)gsrc;

    #pragma unroll 1
    for (int t = 0; t < T_IN; ++t) {
        if ((t & 7) == 0) {
            int row = lane >> 2, si = (lane & 3) * 2;
            *(float2*)(sXw + (si + 0) * 128 + row * 8) = make_float2(pf.x, pf.y);
            *(float2*)(sXw + (si + 1) * 128 + row * 8) = make_float2(pf.z, pf.w);
            if (t < T_IN - 8)
                pf = *(const float4*)(gsrc + ((t >> 3) + 1) * 16);
        }
        float2 xv = *(const float2*)(sXw + (t & 7) * 128 + c * 8);
        do_step<false>(haddr, hwr, fragp, b2p,
                       pk((__bf16)xv.x, (__bf16)xv.y), bias1, q0,
                       cst, wf0, wf1, s0t, s1t);
    }

    // ============ switch to decoder weights ============
    __syncthreads();
    stage_frags(WhhD, WihD, bihD, bhhD);
    __syncthreads();

    #pragma unroll
    for (int tc = 0; tc < 4; ++tc) {
        wf0[tc] = Wfc[c + 16 * tc];        // Wfc[0][col]
        wf1[tc] = Wfc[64 + c + 16 * tc];   // Wfc[1][col]
    }
    const float bfc0 = bfc[0], bfc1 = bfc[1];

    float2 x127 = *(const float2*)(sXw + 7 * 128 + c * 8);   // input_seq[:, -1]
    uint32_t xpack = pk((__bf16)x127.x, (__bf16)x127.y);

    // ================= decoder =================
    #pragma unroll 1
    for (int td = 0; td < T_OUT; ++td) {
        #pragma unroll
        for (int r = 0; r < 4; ++r) { s0t[r] = 0.f; s1t[r] = 0.f; }
        do_step<true>(haddr, hwr, fragp, b2p, xpack, bias1, q0,
                      cst, wf0, wf1, s0t, s1t);
        #pragma unroll
        for (int m = 1; m <= 8; m <<= 1) {
            #pragma unroll
            for (int r = 0; r < 4; ++r) {
                s0t[r] += __shfl_xor(s0t[r], m, 64);
                s1t[r] += __shfl_xor(s1t[r], m, 64);
            }
        }
        float x0n[4], x1n[4];
        #pragma unroll
        for (int r = 0; r < 4; ++r) {
            x0n[r] = rcp_f(1.f + ex2(__builtin_fmaf(-LOG2E, s0t[r], -LOG2E * bfc0)));
            x1n[r] = rcp_f(1.f + ex2(__builtin_fmaf(-LOG2E, s1t[r], -LOG2E * bfc1)));
        }
        if (c == 0) {
            #pragma unroll
            for (int r = 0; r < 4; ++r) {
                *(float2*)(out + ((size_t)(rowBase + 4 * q + r) * T_OUT + td) * 2)
                    = make_float2(x0n[r], x1n[r]);
            }
        }
        // route x(row c) to this lane: after the butterfly, lane (c>>2)*16
        // holds row c's value in register index (c&3)
        float t0[4], t1[4];
        #pragma unroll
        for (int r = 0; r < 4; ++r) {
            t0[r] = __shfl(x0n[r], (c >> 2) << 4, 64);
            t1[r] = __shfl(x1n[r], (c >> 2) << 4, 64);
        }
        float xa = (c & 2) ? ((c & 1) ? t0[3] : t0[2]) : ((c & 1) ? t0[1] : t0[0]);
        float xb = (c & 2) ? ((c & 1) ? t1[3] : t1[2]) : ((c & 1) ? t1[1] : t1[0]);
        xpack = pk((__bf16)xa, (__bf16)xb);
    }
}

extern "C" void kernel_launch(void* const* d_in, const int* in_sizes, int n_in,
                              void* d_out, int out_size, void* d_ws, size_t ws_size,
                              hipStream_t stream) {
    const float* in_seq = (const float*)d_in[0];
    const float* WihE = (const float*)d_in[1];
    const float* WhhE = (const float*)d_in[2];
    const float* bihE = (const float*)d_in[3];
    const float* bhhE = (const float*)d_in[4];
    const float* WihD = (const float*)d_in[5];
    const float* WhhD = (const float*)d_in[6];
    const float* bihD = (const float*)d_in[7];
    const float* bhhD = (const float*)d_in[8];
    const float* Wfc  = (const float*)d_in[9];
    const float* bfcp = (const float*)d_in[10];
    float* out = (float*)d_out;

    const int B = in_sizes[0] / (T_IN * 2);   // 131072
    dim3 grid(B / (NW * 16)), block(NW * 64); // 64 rows/block (4 waves x 16)
    hipLaunchKernelGGL(seq2seq_lstm, grid, block, 0, stream,
                       in_seq, WihE, WhhE, bihE, bhhE,
                       WihD, WhhD, bihD, bhhD, Wfc, bfcp, out);
}

// Round 6
// 4124.926 us; speedup vs baseline: 2.0577x; 2.0577x over previous
//
#include <hip/hip_runtime.h>
#include <stdint.h>

#define T_IN  128
#define T_OUT 50
#define NW    4          // waves per block (256 threads)

typedef __bf16 bf16x8_t __attribute__((ext_vector_type(8)));
typedef float  f32x4_t  __attribute__((ext_vector_type(4)));

#define HROW_BYTES 176
#define HBUF_WAVE  (16 * HROW_BYTES)   // 2816 B per wave

#define LOG2E  1.4426950408889634f
#define LOG2E2 2.8853900817779268f

__device__ __forceinline__ float rcp_f(float x) { return __builtin_amdgcn_rcpf(x); }
__device__ __forceinline__ float ex2(float x)   { return __builtin_amdgcn_exp2f(x); }
__device__ __forceinline__ uint32_t pk(__bf16 a, __bf16 b) {
    return (uint32_t)__builtin_bit_cast(uint16_t, a) |
           ((uint32_t)__builtin_bit_cast(uint16_t, b) << 16);
}

// MFMA layout (verified m89/m91):
//   A  : A[m = lane&15][k = (lane>>4)*8 + j]
//   B  : B[k = (lane>>4)*8 + j][n = lane&15]
//   C/D: col = lane&15, row = (lane>>4)*4 + reg
// k-permutation pi(p) = (p>>2) + 16*(p&3) applied to both Whh k-columns and h
// stores. Slab2 ([x0,x1,1,0...]) identity layout; its 16 B-fragments are
// step-invariant -> held in REGISTERS (loaded once per phase).
//
// exp2 folding: weights/bias pre-scaled by log2e (i,f,o) / 2*log2e (g).
//
// REGISTER BUDGET (rounds 2/3/5 post-mortem): demand ~192+ regs; caps of
// 128 and 170 both spill catastrophically (28-31 GB scratch traffic).
// (256,2) -> cap 256 is the ONLY no-spill occupancy. This round keeps that
// cap and buys ILP instead: two-phase step (all-16-tile MFMA into acc[16],
// then one activation pass with 16 independent chains).

template<bool DEC>
__device__ __forceinline__ void do_step(
    const uint8_t* __restrict__ haddr,  // hb + c*HROW + q*16   (A-frag base)
    uint8_t* __restrict__ hwr,          // hb + 4q*HROW + c*8   (h-store base)
    const uint8_t* __restrict__ fragp,  // sFrag + lane*16
    const bf16x8_t (&b2f)[16],          // slab2 B-frags (registers)
    uint32_t xpack, uint32_t bias1, bool q0,
    f32x4_t (&cst)[4],
    const float (&wf0)[4], const float (&wf1)[4],
    float (&s0)[4], float (&s1)[4])
{
    bf16x8_t a0 = *(const bf16x8_t*)(haddr);
    bf16x8_t a1 = *(const bf16x8_t*)(haddr + 64);
    union { bf16x8_t v; uint32_t u[4]; } ua;
    ua.u[0] = q0 ? xpack : 0u;
    ua.u[1] = bias1;                 // bf16 1.0 at k=2 (q==0 lanes)
    ua.u[2] = 0u; ua.u[3] = 0u;
    bf16x8_t a2 = ua.v;

    // ---- phase 1: all 16 tiles' MFMAs (dense, no VALU interleave) ----
    f32x4_t acc[16];
    #pragma unroll
    for (int t = 0; t < 16; ++t) {
        bf16x8_t b0 = *(const bf16x8_t*)(fragp + t * 2048);
        bf16x8_t b1 = *(const bf16x8_t*)(fragp + t * 2048 + 1024);
        f32x4_t z = {0.f, 0.f, 0.f, 0.f};
        f32x4_t a = __builtin_amdgcn_mfma_f32_16x16x32_bf16(a0, b0, z, 0, 0, 0);
        a = __builtin_amdgcn_mfma_f32_16x16x32_bf16(a1, b1, a, 0, 0, 0);
        acc[t] = __builtin_amdgcn_mfma_f32_16x16x32_bf16(a2, b2f[t], a, 0, 0, 0);
    }

    // ---- phase 2: activations, 16 independent chains ----
    uint32_t hx[4], hy[4];
    f32x4_t hvprev;
    #pragma unroll
    for (int tc = 0; tc < 4; ++tc) {
        float ec[4], ogs[4];
        f32x4_t hv;
        #pragma unroll
        for (int r = 0; r < 4; ++r) {
            float ea  = ex2(-acc[tc][r]);          // bare exp2 (pre-scaled wts)
            float efv = ex2(-acc[tc + 4][r]);
            float egv = ex2(-acc[tc + 8][r]);      // g pre-scaled by 2*log2e
            float eov = ex2(-acc[tc + 12][r]);
            float pa = 1.f + ea, pfv = 1.f + efv, pg = 1.f + egv, po = 1.f + eov;
            float A  = pa * pg, Bq = pfv * po;
            float rr = rcp_f(A * Bq);
            float rA = rr * A;                     // = 1/(pf*po)
            float rB = rr * Bq;                    // = 1/(pa*pg)
            float igp = (1.f - egv) * rB;          // = i*g
            float fgt = rA * po;                   // = sigmoid(f)
            float ogt = rA * pfv;                  // = sigmoid(o)
            float cn  = fgt * cst[tc][r] + igp;
            cst[tc][r] = cn;
            float y = fminf(fmaxf(cn * LOG2E2, -43.f), 43.f);
            ec[r]  = ex2(-y);
            ogs[r] = ogt;
        }
        #pragma unroll
        for (int rp = 0; rp < 2; ++rp) {
            float e0 = ec[2 * rp], e1 = ec[2 * rp + 1];
            float C0 = 1.f + e0, C1 = 1.f + e1;
            float rr2 = rcp_f(C0 * C1);
            hv[2 * rp]     = ogs[2 * rp]     * (1.f - e0) * rr2 * C1;
            hv[2 * rp + 1] = ogs[2 * rp + 1] * (1.f - e1) * rr2 * C0;
        }
        if constexpr (DEC) {
            #pragma unroll
            for (int r = 0; r < 4; ++r) {
                s0[r] += hv[r] * wf0[tc];
                s1[r] += hv[r] * wf1[tc];
            }
        }
        // incremental h-pack (no 16-reg hst array)
        if (tc == 0 || tc == 2) {
            hvprev = hv;
        } else if (tc == 1) {
            #pragma unroll
            for (int r = 0; r < 4; ++r) hx[r] = pk((__bf16)hvprev[r], (__bf16)hv[r]);
        } else {
            #pragma unroll
            for (int r = 0; r < 4; ++r) hy[r] = pk((__bf16)hvprev[r], (__bf16)hv[r]);
        }
    }
    #pragma unroll
    for (int r = 0; r < 4; ++r) {
        uint2 u; u.x = hx[r]; u.y = hy[r];
        *(uint2*)(hwr + r * HROW_BYTES) = u;
    }
}

__global__ __launch_bounds__(256, 2) void seq2seq_lstm(
    const float* __restrict__ in_seq,
    const float* __restrict__ WihE, const float* __restrict__ WhhE,
    const float* __restrict__ bihE, const float* __restrict__ bhhE,
    const float* __restrict__ WihD, const float* __restrict__ WhhD,
    const float* __restrict__ bihD, const float* __restrict__ bhhD,
    const float* __restrict__ Wfc,  const float* __restrict__ bfc,
    float* __restrict__ out)
{
    __shared__ __align__(16) uint8_t sFrag[32768];          // 32 Whh B-frags
    __shared__ __align__(16) uint8_t sB2[4096];             // slab2, 32-slot padded
    __shared__ __align__(16) uint8_t sHbuf[NW * HBUF_WAVE]; // 11264
    __shared__ __align__(16) uint8_t sXbuf[NW * 1024];      // 4096
    // total 52224 B -> 2 blocks/CU (8 waves/CU) at VGPR cap 256

    const int tid  = threadIdx.x;
    const int lane = tid & 63;
    const int wave = tid >> 6;
    const int c    = lane & 15;
    const int q    = lane >> 4;

    auto stage_frags = [&](const float* Whh, const float* Wih,
                           const float* bih, const float* bhh) {
        #pragma unroll 1
        for (int it = 0; it < 8; ++it) {
            int idx = it * 256 + tid;   // 0..2047 = frag(0..31) x lane(0..63)
            int ln  = idx & 63;
            int fg  = idx >> 6;         // fg = tile*2 + kf
            int kf  = fg & 1;
            int t   = fg >> 1;
            int n   = ln & 15;
            int qq  = ln >> 4;
            float sc = ((t >> 2) == 2) ? LOG2E2 : LOG2E;   // g-gate: 2*log2e
            const float* wr = Whh + (t * 16 + n) * 64;
            uint32_t wv[4];
            #pragma unroll
            for (int jj = 0; jj < 4; ++jj) {
                int p0 = kf * 32 + qq * 8 + 2 * jj;
                int p1 = p0 + 1;
                int k0 = (p0 >> 2) + 16 * (p0 & 3);
                int k1 = (p1 >> 2) + 16 * (p1 & 3);
                wv[jj] = pk((__bf16)(sc * wr[k0]), (__bf16)(sc * wr[k1]));
            }
            uint32_t* d = (uint32_t*)(sFrag + fg * 1024 + ln * 16);
            d[0] = wv[0]; d[1] = wv[1]; d[2] = wv[2]; d[3] = wv[3];
        }
        // slab2: tile t at t*256, 32 slots x 8 B; slots 0..15 = {Wih row, bias}
        #pragma unroll 1
        for (int it = 0; it < 2; ++it) {
            int idx = it * 256 + tid;   // 0..511 = tile(0..15) x slot(0..31)
            int t  = idx >> 5;
            int sl = idx & 31;
            float sc = ((t >> 2) == 2) ? LOG2E2 : LOG2E;
            uint2 u = make_uint2(0u, 0u);
            if (sl < 16) {
                int n2 = t * 16 + sl;
                u.x = pk((__bf16)(sc * Wih[n2 * 2 + 0]), (__bf16)(sc * Wih[n2 * 2 + 1]));
                u.y = pk((__bf16)(sc * (bih[n2] + bhh[n2])), (__bf16)0.0f);
            }
            *(uint2*)(sB2 + t * 256 + sl * 8) = u;
        }
    };

    stage_frags(WhhE, WihE, bihE, bhhE);
    for (int i = tid; i < (NW * HBUF_WAVE) / 4; i += 256)
        ((uint32_t*)sHbuf)[i] = 0u;
    __syncthreads();
    // ---- no barriers inside the time loops: each wave owns its 16 rows ----

    uint8_t* hb  = sHbuf + wave * HBUF_WAVE;
    uint8_t* sXw = sXbuf + wave * 1024;
    const int rowBase = blockIdx.x * (NW * 16) + wave * 16;

    const uint8_t* haddr = hb + c * HROW_BYTES + q * 16;
    uint8_t*       hwr   = hb + 4 * q * HROW_BYTES + c * 8;
    const uint8_t* fragp = sFrag + lane * 16;
    const uint8_t* b2p   = sB2 + (lane < 31 ? lane : 31) * 8;
    const uint32_t bias1 = (q == 0) ? 0x00003F80u : 0u;
    const bool     q0    = (q == 0);

    // slab2 B-frags -> registers (step-invariant within a phase)
    bf16x8_t b2f[16];
    auto load_b2 = [&]() {
        #pragma unroll
        for (int t = 0; t < 16; ++t) {
            uint2 w2 = *(const uint2*)(b2p + t * 256);
            union { bf16x8_t v; uint32_t u[4]; } ub;
            ub.u[0] = w2.x; ub.u[1] = w2.y; ub.u[2] = 0u; ub.u[3] = 0u;
            b2f[t] = ub.v;
        }
    };
    load_b2();

    f32x4_t cst[4];
    #pragma unroll
    for (int tc = 0; tc < 4; ++tc) cst[tc] = (f32x4_t){0.f, 0.f, 0.f, 0.f};

    float wf0[4] = {0.f, 0.f, 0.f, 0.f}, wf1[4] = {0.f, 0.f, 0.f, 0.f};
    float s0t[4], s1t[4];

    // ================= encoder (8-step input chunks) =================
    const float* gsrc = in_seq + (size_t)(rowBase + (lane >> 2)) * (T_IN * 2)
                               + (lane & 3) * 4;
    float4 pf = *(const float4*)gsrc;

    #pragma unroll 1
    for (int t = 0; t < T_IN; ++t) {
        if ((t & 7) == 0) {
            int row = lane >> 2, si = (lane & 3) * 2;
            *(float2*)(sXw + (si + 0) * 128 + row * 8) = make_float2(pf.x, pf.y);
            *(float2*)(sXw + (si + 1) * 128 + row * 8) = make_float2(pf.z, pf.w);
            if (t < T_IN - 8)
                pf = *(const float4*)(gsrc + ((t >> 3) + 1) * 16);
        }
        float2 xv = *(const float2*)(sXw + (t & 7) * 128 + c * 8);
        do_step<false>(haddr, hwr, fragp, b2f,
                       pk((__bf16)xv.x, (__bf16)xv.y), bias1, q0,
                       cst, wf0, wf1, s0t, s1t);
    }

    // ============ switch to decoder weights ============
    __syncthreads();
    stage_frags(WhhD, WihD, bihD, bhhD);
    __syncthreads();
    load_b2();

    #pragma unroll
    for (int tc = 0; tc < 4; ++tc) {
        wf0[tc] = Wfc[c + 16 * tc];        // Wfc[0][col]
        wf1[tc] = Wfc[64 + c + 16 * tc];   // Wfc[1][col]
    }
    const float bfc0 = bfc[0], bfc1 = bfc[1];

    float2 x127 = *(const float2*)(sXw + 7 * 128 + c * 8);   // input_seq[:, -1]
    uint32_t xpack = pk((__bf16)x127.x, (__bf16)x127.y);

    // ================= decoder =================
    #pragma unroll 1
    for (int td = 0; td < T_OUT; ++td) {
        #pragma unroll
        for (int r = 0; r < 4; ++r) { s0t[r] = 0.f; s1t[r] = 0.f; }
        do_step<true>(haddr, hwr, fragp, b2f, xpack, bias1, q0,
                      cst, wf0, wf1, s0t, s1t);
        #pragma unroll
        for (int m = 1; m <= 8; m <<= 1) {
            #pragma unroll
            for (int r = 0; r < 4; ++r) {
                s0t[r] += __shfl_xor(s0t[r], m, 64);
                s1t[r] += __shfl_xor(s1t[r], m, 64);
            }
        }
        float x0n[4], x1n[4];
        #pragma unroll
        for (int r = 0; r < 4; ++r) {
            x0n[r] = rcp_f(1.f + ex2(__builtin_fmaf(-LOG2E, s0t[r], -LOG2E * bfc0)));
            x1n[r] = rcp_f(1.f + ex2(__builtin_fmaf(-LOG2E, s1t[r], -LOG2E * bfc1)));
        }
        if (c == 0) {
            #pragma unroll
            for (int r = 0; r < 4; ++r) {
                *(float2*)(out + ((size_t)(rowBase + 4 * q + r) * T_OUT + td) * 2)
                    = make_float2(x0n[r], x1n[r]);
            }
        }
        // route x(row c) to this lane: after the butterfly, lane (c>>2)*16
        // holds row c's value in register index (c&3)
        float t0[4], t1[4];
        #pragma unroll
        for (int r = 0; r < 4; ++r) {
            t0[r] = __shfl(x0n[r], (c >> 2) << 4, 64);
            t1[r] = __shfl(x1n[r], (c >> 2) << 4, 64);
        }
        float xa = (c & 2) ? ((c & 1) ? t0[3] : t0[2]) : ((c & 1) ? t0[1] : t0[0]);
        float xb = (c & 2) ? ((c & 1) ? t1[3] : t1[2]) : ((c & 1) ? t1[1] : t1[0]);
        xpack = pk((__bf16)xa, (__bf16)xb);
    }
}

extern "C" void kernel_launch(void* const* d_in, const int* in_sizes, int n_in,
                              void* d_out, int out_size, void* d_ws, size_t ws_size,
                              hipStream_t stream) {
    const float* in_seq = (const float*)d_in[0];
    const float* WihE = (const float*)d_in[1];
    const float* WhhE = (const float*)d_in[2];
    const float* bihE = (const float*)d_in[3];
    const float* bhhE = (const float*)d_in[4];
    const float* WihD = (const float*)d_in[5];
    const float* WhhD = (const float*)d_in[6];
    const float* bihD = (const float*)d_in[7];
    const float* bhhD = (const float*)d_in[8];
    const float* Wfc  = (const float*)d_in[9];
    const float* bfcp = (const float*)d_in[10];
    float* out = (float*)d_out;

    const int B = in_sizes[0] / (T_IN * 2);   // 131072
    dim3 grid(B / (NW * 16)), block(NW * 64); // 64 rows/block (4 waves x 16)
    hipLaunchKernelGGL(seq2seq_lstm, grid, block, 0, stream,
                       in_seq, WihE, WhhE, bihE, bhhE,
                       WihD, WhhD, bihD, bhhD, Wfc, bfcp, out);
}

// Round 7
// 2968.552 us; speedup vs baseline: 2.8593x; 1.3895x over previous
//
#include <hip/hip_runtime.h>
#include <stdint.h>

#define T_IN  128
#define T_OUT 50
#define NW    4                         // waves per block (256 threads)
#define RPW   32                        // batch rows per wave
#define HROW_BYTES 176                  // 128B h-row + pad (44 dwords, odd-ish stride)
#define HBUF_WAVE  (RPW * HROW_BYTES)   // 5632 B

typedef __bf16 bf16x8_t __attribute__((ext_vector_type(8)));
typedef float  f32x16_t __attribute__((ext_vector_type(16)));

#define LOG2E  1.4426950408889634f
#define LOG2E2 2.8853900817779268f

__device__ __forceinline__ float rcp_f(float x) { return __builtin_amdgcn_rcpf(x); }
__device__ __forceinline__ float ex2(float x)   { return __builtin_amdgcn_exp2f(x); }
__device__ __forceinline__ uint32_t pk(__bf16 a, __bf16 b) {
    return (uint32_t)__builtin_bit_cast(uint16_t, a) |
           ((uint32_t)__builtin_bit_cast(uint16_t, b) << 16);
}
#define MFMA32(A, B, C) __builtin_amdgcn_mfma_f32_32x32x16_bf16(A, B, C, 0, 0, 0)
#define ZERO16 (f32x16_t){0.f,0.f,0.f,0.f,0.f,0.f,0.f,0.f,0.f,0.f,0.f,0.f,0.f,0.f,0.f,0.f}

// 32x32x16 MFMA layouts:
//   C/D (HW-verified m74/m101): col = lane&31, row = (reg&3)+8*(reg>>2)+4*(lane>>5)
//   A (inferred, 2xK pattern): A[m = lane&31][k = (lane>>5)*8 + j]
//   B (inferred):              B[k = (lane>>5)*8 + j][n = lane&31]
// Tiles: t = hf*4 + g  (g: 0=i,1=f,2=g,3=o; hf = unit col-half).
// Gate col of (t, n) = g*64 + hf*32 + n. Identity k-mapping (h stored in unit
// order; A reads unit order) -> no permutation needed.
//
// exp2 folding: Whh/Wih/bias pre-scaled by log2e (i,f,o) / 2*log2e (g).
//
// REGISTER BUDGET (r2/r3/r5/r6 post-mortems): cap 256 is the only no-spill
// regime; headroom over the r4 layout is ~60 regs. Here: acc 64 (one col-half
// at a time) + cst 32 + A-frags 20 + dec sums 32 + misc ~40 = ~190. LDS
// traffic (the r4 co-bottleneck): 32 b128 B-frags now cover 32 rows, not 16.

template<bool DEC>
__device__ __forceinline__ void do_step(
    uint8_t* __restrict__ hb,           // wave's h buffer
    const uint8_t* __restrict__ fragp,  // sFrag + lane*16
    const uint8_t* __restrict__ b2p,    // sB2 + lane*16
    int m, int kh, uint32_t xpack,
    f32x16_t& cstA, f32x16_t& cstB,
    float wfa0, float wfa1, float wfb0, float wfb1,
    float (&s0)[16], float (&s1)[16])
{
    // A-frags: row m, k-groups 0..3 (units kk*16 + kh*8 + j)
    const uint8_t* ha = hb + m * HROW_BYTES + kh * 16;
    bf16x8_t a0 = *(const bf16x8_t*)(ha);
    bf16x8_t a1 = *(const bf16x8_t*)(ha + 32);
    bf16x8_t a2 = *(const bf16x8_t*)(ha + 64);
    bf16x8_t a3 = *(const bf16x8_t*)(ha + 96);
    union { bf16x8_t v; uint32_t u[4]; } ux;
    ux.u[0] = kh ? 0u : xpack;          // k=0,1 : x0, x1
    ux.u[1] = kh ? 0u : 0x00003F80u;    // k=2   : 1.0 (bias row)
    ux.u[2] = 0u; ux.u[3] = 0u;
    bf16x8_t ax = ux.v;

    #pragma unroll
    for (int hf = 0; hf < 2; ++hf) {
        f32x16_t acc[4];
        #pragma unroll
        for (int g = 0; g < 4; ++g) {
            const uint8_t* bp = fragp + (hf * 4 + g) * 4096;
            f32x16_t a = MFMA32(a0, *(const bf16x8_t*)(bp), ZERO16);
            a = MFMA32(a1, *(const bf16x8_t*)(bp + 1024), a);
            a = MFMA32(a2, *(const bf16x8_t*)(bp + 2048), a);
            a = MFMA32(a3, *(const bf16x8_t*)(bp + 3072), a);
            bf16x8_t b2 = *(const bf16x8_t*)(b2p + (hf * 4 + g) * 1024);
            acc[g] = MFMA32(ax, b2, a);
        }
        f32x16_t& cs = hf ? cstB : cstA;
        const float w0 = hf ? wfb0 : wfa0;
        const float w1 = hf ? wfb1 : wfa1;
        #pragma unroll
        for (int jp = 0; jp < 8; ++jp) {
            const int j0 = 2 * jp, j1 = 2 * jp + 1;
            float og[2], ec[2];
            #pragma unroll
            for (int jj = 0; jj < 2; ++jj) {
                const int j = j0 + jj;
                float ea  = ex2(-acc[0][j]);     // pre-scaled -> bare exp2
                float efv = ex2(-acc[1][j]);
                float egv = ex2(-acc[2][j]);     // g pre-scaled by 2*log2e
                float eov = ex2(-acc[3][j]);
                float pa = 1.f + ea, pfv = 1.f + efv, pg = 1.f + egv, po = 1.f + eov;
                float A  = pa * pg, Bq = pfv * po;
                float rr = rcp_f(A * Bq);
                float rA = rr * A;               // = 1/(pf*po)
                float rB = rr * Bq;              // = 1/(pa*pg)
                float igp = (1.f - egv) * rB;    // = i*g
                float fgt = rA * po;             // = sigmoid(f)
                float ogt = rA * pfv;            // = sigmoid(o)
                float cn  = fgt * cs[j] + igp;
                cs[j] = cn;
                float y = fminf(fmaxf(cn * LOG2E2, -43.f), 43.f);
                ec[jj] = ex2(-y);
                og[jj] = ogt;
            }
            float C0 = 1.f + ec[0], C1 = 1.f + ec[1];
            float rr2 = rcp_f(C0 * C1);
            float h0 = og[0] * (1.f - ec[0]) * rr2 * C1;
            float h1 = og[1] * (1.f - ec[1]) * rr2 * C0;
            if constexpr (DEC) {
                s0[j0] += h0 * w0; s1[j0] += h0 * w1;
                s0[j1] += h1 * w0; s1[j1] += h1 * w1;
            }
            const int r0 = (j0 & 3) + 8 * (j0 >> 2) + 4 * kh;
            const int r1 = (j1 & 3) + 8 * (j1 >> 2) + 4 * kh;
            *((__bf16*)(hb + r0 * HROW_BYTES + hf * 64) + m) = (__bf16)h0;
            *((__bf16*)(hb + r1 * HROW_BYTES + hf * 64) + m) = (__bf16)h1;
        }
    }
}

__global__ __launch_bounds__(256, 2) void seq2seq_lstm(
    const float* __restrict__ in_seq,
    const float* __restrict__ WihE, const float* __restrict__ WhhE,
    const float* __restrict__ bihE, const float* __restrict__ bhhE,
    const float* __restrict__ WihD, const float* __restrict__ WhhD,
    const float* __restrict__ bihD, const float* __restrict__ bhhD,
    const float* __restrict__ Wfc,  const float* __restrict__ bfc,
    float* __restrict__ out)
{
    __shared__ __align__(16) uint8_t sFrag[32768];          // 8 tiles x 4 kfrags x 1KB
    __shared__ __align__(16) uint8_t sB2[8192];             // 8 tiles x 1KB (x/bias slab)
    __shared__ __align__(16) uint8_t sHbuf[NW * HBUF_WAVE]; // 22528
    __shared__ __align__(16) uint8_t sXbuf[NW * 2048];      // [step0..7][row0..31] f2
    __shared__ __align__(16) uint8_t sXfb[NW * 256];        // decoder x feedback
    // total 72704 B -> 2 blocks/CU (8 waves/CU) at VGPR cap 256

    const int tid  = threadIdx.x;
    const int lane = tid & 63;
    const int wave = tid >> 6;
    const int m    = lane & 31;
    const int kh   = lane >> 5;

    auto stage_frags = [&](const float* Whh, const float* Wih,
                           const float* bih, const float* bhh) {
        #pragma unroll 1
        for (int it = 0; it < 8; ++it) {
            int idx = it * 256 + tid;    // 0..2047 = frag(0..31) x lane(0..63)
            int ln  = idx & 63;
            int fg  = idx >> 6;          // fg = t*4 + kk
            int kk  = fg & 3;
            int t   = fg >> 2;
            int g   = t & 3;
            int hf  = t >> 2;
            int n   = ln & 31;
            int kg  = ln >> 5;
            float sc = (g == 2) ? LOG2E2 : LOG2E;
            const float* wr = Whh + (g * 64 + hf * 32 + n) * 64 + kk * 16 + kg * 8;
            uint32_t wv[4];
            #pragma unroll
            for (int jj = 0; jj < 4; ++jj)
                wv[jj] = pk((__bf16)(sc * wr[2 * jj]), (__bf16)(sc * wr[2 * jj + 1]));
            uint32_t* d = (uint32_t*)(sFrag + t * 4096 + kk * 1024 + ln * 16);
            d[0] = wv[0]; d[1] = wv[1]; d[2] = wv[2]; d[3] = wv[3];
        }
        // slab2 B-frags: B2[k=0]=Wih[col][0], k=1=Wih[col][1], k=2=bias, else 0
        #pragma unroll 1
        for (int it = 0; it < 2; ++it) {
            int idx = it * 256 + tid;    // 0..511 = tile(0..7) x lane(0..63)
            int ln  = idx & 63;
            int t   = idx >> 6;
            int g   = t & 3;
            int hf  = t >> 2;
            int n   = ln & 31;
            int kg  = ln >> 5;
            float sc = (g == 2) ? LOG2E2 : LOG2E;
            uint32_t u0 = 0u, u1 = 0u;
            if (kg == 0) {
                int col = g * 64 + hf * 32 + n;
                u0 = pk((__bf16)(sc * Wih[col * 2 + 0]), (__bf16)(sc * Wih[col * 2 + 1]));
                u1 = pk((__bf16)(sc * (bih[col] + bhh[col])), (__bf16)0.0f);
            }
            uint32_t* d = (uint32_t*)(sB2 + t * 1024 + ln * 16);
            d[0] = u0; d[1] = u1; d[2] = 0u; d[3] = 0u;
        }
    };

    stage_frags(WhhE, WihE, bihE, bhhE);
    for (int i = tid; i < (NW * HBUF_WAVE) / 4; i += 256)
        ((uint32_t*)sHbuf)[i] = 0u;
    __syncthreads();
    // ---- no barriers inside the time loops: each wave owns its 32 rows ----

    uint8_t* hb    = sHbuf + wave * HBUF_WAVE;
    uint8_t* sXw   = sXbuf + wave * 2048;
    uint8_t* sXfbw = sXfb + wave * 256;
    const int rowBase = blockIdx.x * (NW * RPW) + wave * RPW;

    const uint8_t* fragp = sFrag + lane * 16;
    const uint8_t* b2p   = sB2 + lane * 16;

    f32x16_t cstA = ZERO16, cstB = ZERO16;
    float s0[16], s1[16];
    float wfa0 = 0.f, wfa1 = 0.f, wfb0 = 0.f, wfb1 = 0.f;

    // ================= encoder (8-step input chunks) =================
    const float* gsrc = in_seq + (size_t)(rowBase + (lane >> 1)) * (T_IN * 2)
                               + (lane & 1) * 8;
    float4 pf0 = *(const float4*)gsrc;
    float4 pf1 = *(const float4*)(gsrc + 4);

    #pragma unroll 1
    for (int t = 0; t < T_IN; ++t) {
        if ((t & 7) == 0) {
            int row = lane >> 1, sb = (lane & 1) * 4;
            *(float2*)(sXw + (sb + 0) * 256 + row * 8) = make_float2(pf0.x, pf0.y);
            *(float2*)(sXw + (sb + 1) * 256 + row * 8) = make_float2(pf0.z, pf0.w);
            *(float2*)(sXw + (sb + 2) * 256 + row * 8) = make_float2(pf1.x, pf1.y);
            *(float2*)(sXw + (sb + 3) * 256 + row * 8) = make_float2(pf1.z, pf1.w);
            if (t < T_IN - 8) {
                const float* p = gsrc + ((t >> 3) + 1) * 16;
                pf0 = *(const float4*)p;
                pf1 = *(const float4*)(p + 4);
            }
        }
        float2 xv = *(const float2*)(sXw + (t & 7) * 256 + m * 8);
        do_step<false>(hb, fragp, b2p, m, kh,
                       pk((__bf16)xv.x, (__bf16)xv.y),
                       cstA, cstB, wfa0, wfa1, wfb0, wfb1, s0, s1);
    }

    // ============ switch to decoder weights ============
    __syncthreads();
    stage_frags(WhhD, WihD, bihD, bhhD);
    __syncthreads();

    wfa0 = Wfc[m];        wfa1 = Wfc[64 + m];    // units 0..31
    wfb0 = Wfc[32 + m];   wfb1 = Wfc[96 + m];    // units 32..63
    const float nb0 = -LOG2E * bfc[0], nb1 = -LOG2E * bfc[1];

    float2 x127 = *(const float2*)(sXw + 7 * 256 + m * 8);   // input_seq[:, -1]
    uint32_t xpack = pk((__bf16)x127.x, (__bf16)x127.y);

    // ================= decoder =================
    #pragma unroll 1
    for (int td = 0; td < T_OUT; ++td) {
        #pragma unroll
        for (int j = 0; j < 16; ++j) { s0[j] = 0.f; s1[j] = 0.f; }
        do_step<true>(hb, fragp, b2p, m, kh, xpack,
                      cstA, cstB, wfa0, wfa1, wfb0, wfb1, s0, s1);
        // reduce across the 32 lanes of each half (rows live per half-wave)
        #pragma unroll
        for (int msk = 1; msk <= 16; msk <<= 1) {
            #pragma unroll
            for (int j = 0; j < 16; ++j) {
                s0[j] += __shfl_xor(s0[j], msk, 64);
                s1[j] += __shfl_xor(s1[j], msk, 64);
            }
        }
        // writer lanes (m==0 in each half) compute sigmoid, write out + feedback
        if (m == 0) {
            #pragma unroll
            for (int j = 0; j < 16; ++j) {
                int row = (j & 3) + 8 * (j >> 2) + 4 * kh;
                float p0 = rcp_f(1.f + ex2(__builtin_fmaf(-LOG2E, s0[j], nb0)));
                float p1 = rcp_f(1.f + ex2(__builtin_fmaf(-LOG2E, s1[j], nb1)));
                *(float2*)(out + ((size_t)(rowBase + row) * T_OUT + td) * 2)
                    = make_float2(p0, p1);
                *(float2*)(sXfbw + row * 8) = make_float2(p0, p1);
            }
        }
        float2 xv = *(const float2*)(sXfbw + m * 8);   // same-wave LDS handoff
        xpack = pk((__bf16)xv.x, (__bf16)xv.y);
    }
}

extern "C" void kernel_launch(void* const* d_in, const int* in_sizes, int n_in,
                              void* d_out, int out_size, void* d_ws, size_t ws_size,
                              hipStream_t stream) {
    const float* in_seq = (const float*)d_in[0];
    const float* WihE = (const float*)d_in[1];
    const float* WhhE = (const float*)d_in[2];
    const float* bihE = (const float*)d_in[3];
    const float* bhhE = (const float*)d_in[4];
    const float* WihD = (const float*)d_in[5];
    const float* WhhD = (const float*)d_in[6];
    const float* bihD = (const float*)d_in[7];
    const float* bhhD = (const float*)d_in[8];
    const float* Wfc  = (const float*)d_in[9];
    const float* bfcp = (const float*)d_in[10];
    float* out = (float*)d_out;

    const int B = in_sizes[0] / (T_IN * 2);      // 131072
    dim3 grid(B / (NW * RPW)), block(NW * 64);   // 128 rows/block (4 waves x 32)
    hipLaunchKernelGGL(seq2seq_lstm, grid, block, 0, stream,
                       in_seq, WihE, WhhE, bihE, bhhE,
                       WihD, WhhD, bihD, bhhD, Wfc, bfcp, out);
}